// Round 6
// baseline (245.354 us; speedup 1.0000x reference)
//
#include <hip/hip_runtime.h>
#include <hip/hip_bf16.h>

#define S_LEN 8192
#define DM    1024
#define DK    128
#define KSTR  136    // K LDS row stride (shorts): 2-way max bank aliasing
#define VSTR  40     // Vt LDS row stride (shorts), 32-k rows
#define ASTR  68     // proj LDS row stride (shorts): 2-way max
#define SLOTD 2112   // dwords per partial slot: m[32] l[32] fp32 + O[32*128] fp16
#define NCMAX 16     // max partial chunks per 32-row q-tile

typedef __attribute__((ext_vector_type(8))) short bf16x8;
typedef __attribute__((ext_vector_type(8))) _Float16 f16x8;
typedef __attribute__((ext_vector_type(4))) float f32x4;
typedef __attribute__((ext_vector_type(16))) float f32x16;

__device__ __forceinline__ f32x16 mfma32(bf16x8 a, bf16x8 b, f32x16 c) {
    return __builtin_amdgcn_mfma_f32_32x32x16_bf16(a, b, c, 0, 0, 0);
}
__device__ __forceinline__ f32x16 mfma32f(f16x8 a, f16x8 b, f32x16 c) {
    return __builtin_amdgcn_mfma_f32_32x32x16_f16(a, b, c, 0, 0, 0);
}

// fp32 -> bf16 (RNE)
__device__ __forceinline__ ushort f2bf(float f) {
    unsigned u = __builtin_bit_cast(unsigned, f);
    u += 0x7FFFu + ((u >> 16) & 1u);
    return (ushort)(u >> 16);
}

__device__ __forceinline__ ushort f2h(float f) {
    return __builtin_bit_cast(ushort, (_Float16)f);
}

// packed f32 pair -> bf16x2 in one u32 (lo = a, hi = b)
__device__ __forceinline__ uint cvt_pk_bf16(float a, float b) {
    uint r;
    asm("v_cvt_pk_bf16_f32 %0, %1, %2" : "=v"(r) : "v"(a), "v"(b));
    return r;
}

// ---------------------------------------------------------------------------
// Projection GEMM, rebuilt: per block BM=64 rows x one full matrix (128 cols)
// x K=1024. Grid 384 = 128 m-tiles x 3 (which of Q/K/V). XCD-chunk swizzle:
// each XCD gets 16 consecutive m-tiles x 3 matrices -> X rows read once into
// that XCD's L2 and reused 3x. W (fp32) converted to fp16 in-register at
// staging (no separate convert kernel; W panel is L2-resident).
// 4 waves: wave (wm,wn) owns 32m x 64n via 2 mfma32 acc (32 VGPR).
// Double-buffered LDS, reg-staged, ONE barrier per BK=64 iter, 16 iters.
// 43.7 FLOP/staged-byte (vs 15.4 in the BM=16 version measured at 45 us).
// ---------------------------------------------------------------------------
__global__ __launch_bounds__(256)
void proj_gemm_kernel(const float* __restrict__ X,
                      const float* __restrict__ Wq,
                      const float* __restrict__ Wk,
                      const float* __restrict__ Wv,
                      ushort* __restrict__ Qb,
                      ushort* __restrict__ Kb,
                      ushort* __restrict__ Vtb) {
    __shared__ _Float16 Ash[2][64 * ASTR];    // 2 x 8704 B
    __shared__ _Float16 Bsh[2][128 * ASTR];   // 2 x 17408 B (52224 total)

    const int raw = blockIdx.x;
    const int swz = (raw & 7) * 48 + (raw >> 3);   // 384 % 8 == 0: bijective
    const int mb  = swz / 3;
    const int which = swz - mb * 3;
    const float* Wsrc = (which == 0) ? Wq : (which == 1 ? Wk : Wv);
    const int m0 = mb * 64;

    const int tid  = threadIdx.x;
    const int lane = tid & 63;
    const int l31  = lane & 31;
    const int hi   = lane >> 5;
    const int wv   = tid >> 6;
    const int wm   = wv & 1;
    const int wn   = wv >> 1;

    f32x16 acc[2];
#pragma unroll
    for (int j = 0; j < 2; ++j)
#pragma unroll
        for (int r = 0; r < 16; ++r) acc[j][r] = 0.f;

    // staging roles: A 64 rows x 16 granules(4k) = 1024 -> 4/thread
    //                B 128 rows x 16 granules    = 2048 -> 8/thread
    float4 ra[4], rb[8];
#define LOADR(KK)                                                              \
    {                                                                          \
        _Pragma("unroll")                                                      \
        for (int i = 0; i < 4; ++i) {                                          \
            const int s = tid + (i << 8);                                      \
            ra[i] = *(const float4*)(X + (size_t)(m0 + (s >> 4)) * DM + (KK) + (s & 15) * 4); \
        }                                                                      \
        _Pragma("unroll")                                                      \
        for (int i = 0; i < 8; ++i) {                                          \
            const int s = tid + (i << 8);                                      \
            rb[i] = *(const float4*)(Wsrc + (size_t)(s >> 4) * DM + (KK) + (s & 15) * 4); \
        }                                                                      \
    }
#define WRITEB(BUF)                                                            \
    {                                                                          \
        _Pragma("unroll")                                                      \
        for (int i = 0; i < 4; ++i) {                                          \
            const int s = tid + (i << 8);                                      \
            union { _Float16 h[4]; uint2 u; } p_;                              \
            p_.h[0] = (_Float16)ra[i].x; p_.h[1] = (_Float16)ra[i].y;          \
            p_.h[2] = (_Float16)ra[i].z; p_.h[3] = (_Float16)ra[i].w;          \
            *(uint2*)(Ash[BUF] + (s >> 4) * ASTR + (s & 15) * 4) = p_.u;       \
        }                                                                      \
        _Pragma("unroll")                                                      \
        for (int i = 0; i < 8; ++i) {                                          \
            const int s = tid + (i << 8);                                      \
            union { _Float16 h[4]; uint2 u; } p_;                              \
            p_.h[0] = (_Float16)rb[i].x; p_.h[1] = (_Float16)rb[i].y;          \
            p_.h[2] = (_Float16)rb[i].z; p_.h[3] = (_Float16)rb[i].w;          \
            *(uint2*)(Bsh[BUF] + (s >> 4) * ASTR + (s & 15) * 4) = p_.u;       \
        }                                                                      \
    }
#define COMPUTE(BUF)                                                           \
    {                                                                          \
        const _Float16* As_ = Ash[BUF] + (wm * 32 + l31) * ASTR + hi * 8;      \
        const _Float16* Bs_ = Bsh[BUF] + (wn * 64 + l31) * ASTR + hi * 8;      \
        __builtin_amdgcn_s_setprio(1);                                         \
        _Pragma("unroll")                                                      \
        for (int ks = 0; ks < 4; ++ks) {                                       \
            const f16x8 af_ = *(const f16x8*)(As_ + ks * 16);                  \
            _Pragma("unroll")                                                  \
            for (int j = 0; j < 2; ++j) {                                      \
                const f16x8 bf_ = *(const f16x8*)(Bs_ + j * 32 * ASTR + ks * 16); \
                acc[j] = mfma32f(af_, bf_, acc[j]);                            \
            }                                                                  \
        }                                                                      \
        __builtin_amdgcn_s_setprio(0);                                         \
    }

    LOADR(0)
    WRITEB(0)
    __syncthreads();
    for (int it = 0; it < 16; ++it) {
        const int cur = it & 1;
        if (it < 15) LOADR((it + 1) * 64)
        COMPUTE(cur)
        if (it < 15) WRITEB(cur ^ 1)
        __syncthreads();
    }
#undef LOADR
#undef WRITEB
#undef COMPUTE

    // ---- epilogue ----
    const float scq = 0.088388347648318447f * 1.4426950408889634f;
#pragma unroll
    for (int j = 0; j < 2; ++j) {
        const int n = wn * 64 + j * 32 + l31;       // 0..127 within matrix
        if (which == 2) {
            // V transposed: col n fixed per lane; rows in 4-consecutive groups
#pragma unroll
            for (int rq = 0; rq < 4; ++rq) {
                union { ushort h[4]; uint2 u; } p;
#pragma unroll
                for (int d = 0; d < 4; ++d) p.h[d] = f2bf(acc[j][4 * rq + d]);
                *(uint2*)(Vtb + (size_t)n * S_LEN + m0 + wm * 32 + 8 * rq + 4 * hi) = p.u;
            }
        } else {
            ushort* Ob = (which == 0) ? Qb : Kb;
            const float sc = (which == 0) ? scq : 1.0f;
#pragma unroll
            for (int r = 0; r < 16; ++r) {
                const int row = m0 + wm * 32 + (r & 3) + 8 * (r >> 2) + 4 * hi;
                Ob[(size_t)row * DK + n] = f2bf(acc[j][r] * sc);
            }
        }
    }
}

// ---------------------------------------------------------------------------
// Flash attention partials — same verified 32x32 swapped-both-ways math as r4,
// with KVBLK 64 -> 32: LDS 71.7 KB -> 37.9 KB -> 4 blocks/CU (16 waves/CU vs
// 8). Theory: flash has been latency-bound at 2 waves/SIMD across 3 structural
// rewrites; occupancy is the untested gate.
// ---------------------------------------------------------------------------
__global__ __launch_bounds__(256, 4)
void flash_partial_kernel(const ushort* __restrict__ Qg,
                          const ushort* __restrict__ Kg,
                          const ushort* __restrict__ Vtg,
                          float* __restrict__ Part) {
    __shared__ __align__(16) ushort Ks [2][32 * KSTR];   // 2 x 8704 B
    __shared__ __align__(16) ushort Vts[2][128 * VSTR];  // 2 x 10240 B (37888 total)

    // decode (qb, chunk): NC(qb) = (2qb+9)>>3, 544 blocks, heavy-first
    int rem = 543 - (int)blockIdx.x;
    int qb = 0;
    for (;;) {
        const int nc = (2 * qb + 9) >> 3;
        if (rem < nc) break;
        rem -= nc; ++qb;
    }
    const int NC    = (2 * qb + 9) >> 3;
    const int chunk = rem;
    const int nkt   = 4 * qb + 4;          // 32-wide K tiles
    const int kt_lo = chunk * nkt / NC;
    const int kt_hi = (chunk + 1) * nkt / NC;

    const int tid  = threadIdx.x;
    const int wv   = tid >> 6;
    const int lane = tid & 63;
    const int l31  = lane & 31;
    const int hi   = lane >> 5;
    const int q0w  = qb * 128 + wv * 32;
    const int qrow = q0w + l31;

    // Q resident (B-frag: col=q=l31, d = hi*8 + e per 16-d chunk i)
    bf16x8 qf[8];
    {
        const ushort* qp = Qg + (size_t)qrow * DK + hi * 8;
#pragma unroll
        for (int i = 0; i < 8; ++i) qf[i] = *(const bf16x8*)(qp + i * 16);
    }

    float m_ = -__builtin_inff();
    float l_ = 0.f;
    f32x16 acc[4];
#pragma unroll
    for (int dt = 0; dt < 4; ++dt)
#pragma unroll
        for (int j = 0; j < 16; ++j) acc[dt][j] = 0.f;

    bf16x8 stg[4];
#define LOAD_TILE(K0)                                                          \
    {                                                                          \
        const int k0_ = (K0);                                                  \
        _Pragma("unroll")                                                      \
        for (int i = 0; i < 4; ++i) {                                          \
            const int c = tid + (i << 8);                                      \
            if (c < 512) {                                                     \
                const int row = c >> 4, ch = c & 15;                           \
                stg[i] = *(const bf16x8*)(Kg + (size_t)(k0_ + row) * DK + ch * 8); \
            } else {                                                           \
                const int cc = c - 512;                                        \
                const int row = cc >> 2, ch = cc & 3;                          \
                stg[i] = *(const bf16x8*)(Vtg + (size_t)row * S_LEN + k0_ + ch * 8); \
            }                                                                  \
        }                                                                      \
    }
    // V stored pi-permuted (32-k restriction of the verified r4 mapping):
    // chunk ch (k = 8ch+m): s_lo = 4(ch&1)+16(ch>>1); m 0..3 at s_lo, 4..7 at +8
#define WRITE_BUF(B)                                                           \
    {                                                                          \
        ushort* Kb_ = Ks[B]; ushort* Vb_ = Vts[B];                             \
        _Pragma("unroll")                                                      \
        for (int i = 0; i < 4; ++i) {                                          \
            const int c = tid + (i << 8);                                      \
            if (c < 512) {                                                     \
                const int row = c >> 4, ch = c & 15;                           \
                *(bf16x8*)(Kb_ + row * KSTR + ch * 8) = stg[i];                \
            } else {                                                           \
                const int cc = c - 512;                                        \
                const int row = cc >> 2, ch = cc & 3;                          \
                const int s_lo = ((ch & 1) << 2) + ((ch >> 1) << 4);           \
                union { bf16x8 v; uint2 q2[2]; } u;                            \
                u.v = stg[i];                                                  \
                ushort* vb = Vb_ + row * VSTR + s_lo;                          \
                *(uint2*)vb       = u.q2[0];                                   \
                *(uint2*)(vb + 8) = u.q2[1];                                   \
            }                                                                  \
        }                                                                      \
    }

    LOAD_TILE(kt_lo * 32)
    WRITE_BUF(0)
    if (kt_lo + 1 < kt_hi) LOAD_TILE((kt_lo + 1) * 32)
    __syncthreads();

    for (int kt = kt_lo; kt < kt_hi; ++kt) {
        const int k0 = kt * 32;
        const int cb = (kt - kt_lo) & 1;
        const ushort* ks = Ks[cb];
        const ushort* vs = Vts[cb];
        const bool prc = (k0 <= q0w);   // else tile fully masked for this wave

        f32x16 Sr0;
        if (prc) {
            __builtin_amdgcn_s_setprio(1);
#pragma unroll
            for (int j = 0; j < 16; ++j) Sr0[j] = 0.f;
            const ushort* ka0 = ks + l31 * KSTR + hi * 8;
#pragma unroll
            for (int i = 0; i < 8; ++i)
                Sr0 = mfma32(*(const bf16x8*)(ka0 + i * 16), qf[i], Sr0);
            __builtin_amdgcn_s_setprio(0);
        }

        // stage next tile into other buffer; prefetch tile after into regs
        if (kt + 1 < kt_hi) {
            WRITE_BUF(cb ^ 1)
            if (kt + 2 < kt_hi) LOAD_TILE((kt + 2) * 32)
        }

        if (prc) {
            // ---- causal mask (diagonal region only) ----
            if (k0 + 31 > q0w) {
#pragma unroll
                for (int r = 0; r < 16; ++r) {
                    const int krow = (r & 3) + 8 * (r >> 2) + 4 * hi;
                    if (k0 + krow > qrow) Sr0[r] = -__builtin_inff();
                }
            }

            // ---- online softmax, q lane-local ----
            float pmax = Sr0[0];
#pragma unroll
            for (int r = 1; r < 16; ++r) pmax = fmaxf(pmax, Sr0[r]);
            pmax = fmaxf(pmax, __shfl_xor(pmax, 32));
            if (__any(pmax > m_ + 8.f)) {
                const float mnew = fmaxf(m_, pmax);
                const float al = __builtin_amdgcn_exp2f(m_ - mnew);
                m_ = mnew;
                l_ *= al;
#pragma unroll
                for (int dt = 0; dt < 4; ++dt)
#pragma unroll
                    for (int j = 0; j < 16; ++j) acc[dt][j] *= al;
            }
            float rs = 0.f;
            uint pfa[8];
            {
                float p0[16];
#pragma unroll
                for (int r = 0; r < 16; ++r) { p0[r] = __builtin_amdgcn_exp2f(Sr0[r] - m_); rs += p0[r]; }
#pragma unroll
                for (int j = 0; j < 4; ++j) {
                    pfa[j]     = cvt_pk_bf16(p0[2 * j],     p0[2 * j + 1]);
                    pfa[4 + j] = cvt_pk_bf16(p0[8 + 2 * j], p0[8 + 2 * j + 1]);
                }
            }
            rs += __shfl_xor(rs, 32);
            l_ += rs;

            // ---- O^T += V^T P^T (A = V pi-stored, B = P from regs) ----
            __builtin_amdgcn_s_setprio(1);
#pragma unroll
            for (int kc = 0; kc < 2; ++kc) {
                union { uint u[4]; bf16x8 v; } pu;
#pragma unroll
                for (int j = 0; j < 4; ++j) pu.u[j] = pfa[4 * kc + j];
                const ushort* va = vs + l31 * VSTR + kc * 16 + hi * 8;
#pragma unroll
                for (int dt = 0; dt < 4; ++dt)
                    acc[dt] = mfma32(*(const bf16x8*)(va + dt * 32 * VSTR), pu.v, acc[dt]);
            }
            __builtin_amdgcn_s_setprio(0);
        }
        __syncthreads();
    }
#undef LOAD_TILE
#undef WRITE_BUF

    // ---- write partial slot (32 q-rows per wave) ----
    const int qt32 = qb * 4 + wv;
    float* slot = Part + (size_t)(qt32 * NCMAX + chunk) * SLOTD;
    if (hi == 0) {
        slot[l31]      = m_;
        slot[32 + l31] = l_;
    }
    // O fp16: lane q = l31; d = 32dt + 8s + 4hi + {0..3} from regs 4s..4s+3
    uint* slotO = (uint*)(slot + 64);
#pragma unroll
    for (int dt = 0; dt < 4; ++dt)
#pragma unroll
        for (int s = 0; s < 4; ++s) {
            uint2 w;
            w.x = (uint)f2h(acc[dt][4 * s])     | ((uint)f2h(acc[dt][4 * s + 1]) << 16);
            w.y = (uint)f2h(acc[dt][4 * s + 2]) | ((uint)f2h(acc[dt][4 * s + 3]) << 16);
            *(uint2*)(slotO + l31 * 64 + dt * 16 + s * 4 + hi * 2) = w;
        }
}

// ---------------------------------------------------------------------------
// Merge <=16 partials per 32-row q-tile, normalize, write output.
// Grid 512: blockIdx = qt*2 + half (each block does 32 of 64 dword-pairs).
// ---------------------------------------------------------------------------
__global__ __launch_bounds__(256)
void flash_merge_kernel(const float* __restrict__ Part, float* __restrict__ Out) {
    __shared__ float Ms[32], Ls[32];
    __shared__ float Sc[16][32];
    const int qt   = blockIdx.x >> 1;    // 0..255
    const int half = blockIdx.x & 1;
    const int qb = qt >> 2;
    const int P  = (2 * qb + 9) >> 3;    // NC(qb)
    const int q0 = qt * 32;
    const int tid = threadIdx.x;
    const float* base = Part + (size_t)qt * NCMAX * SLOTD;

    if (tid < 32) {
        float M = -__builtin_inff();
        for (int p = 0; p < P; ++p) M = fmaxf(M, base[p * SLOTD + tid]);
        float L = 0.f;
        for (int p = 0; p < P; ++p)
            L += base[p * SLOTD + 32 + tid] * exp2f(base[p * SLOTD + tid] - M);
        Ms[tid] = M; Ls[tid] = L;
    }
    __syncthreads();
    for (int j = tid; j < 512; j += 256) {
        const int p = j >> 5, row = j & 31;
        Sc[p][row] = (p < P) ? exp2f(base[p * SLOTD + row] - Ms[row]) : 0.f;
    }
    __syncthreads();

    // 32 rows x 32 dword-pairs (this half) = 1024 items, 4 per thread
#pragma unroll
    for (int j = tid; j < 1024; j += 256) {
        const int row = j >> 5, c2 = (j & 31) + half * 32;
        float o0 = 0.f, o1 = 0.f;
        for (int p = 0; p < P; ++p) {
            const uint u = ((const uint*)(base + p * SLOTD + 64))[row * 64 + c2];
            const float sc = Sc[p][row];
            o0 += (float)__builtin_bit_cast(_Float16, (ushort)(u & 0xFFFF)) * sc;
            o1 += (float)__builtin_bit_cast(_Float16, (ushort)(u >> 16)) * sc;
        }
        const float inv = 1.0f / Ls[row];
        float2 o; o.x = o0 * inv; o.y = o1 * inv;
        *(float2*)(Out + (size_t)(q0 + row) * DK + c2 * 2) = o;
    }
}

extern "C" void kernel_launch(void* const* d_in, const int* in_sizes, int n_in,
                              void* d_out, int out_size, void* d_ws, size_t ws_size,
                              hipStream_t stream) {
    const float* X  = (const float*)d_in[0];
    const float* Wq = (const float*)d_in[1];
    const float* Wk = (const float*)d_in[2];
    const float* Wv = (const float*)d_in[3];
    ushort* ws  = (ushort*)d_ws;
    ushort* Qb  = ws;                          // 8192x128 bf16 (pre-scaled)
    ushort* Kb  = ws + (size_t)S_LEN * DK;     // 8192x128 bf16
    ushort* Vtb = ws + 2 * (size_t)S_LEN * DK; // 128x8192 bf16 (transposed)
    // Partials: 256 qtiles * 16 slots * 8448 B = 34.6 MiB
    float* Part = (float*)(ws + 3 * (size_t)S_LEN * DK);
    float* Out = (float*)d_out;

    proj_gemm_kernel<<<384, 256, 0, stream>>>(X, Wq, Wk, Wv, Qb, Kb, Vtb);
    flash_partial_kernel<<<544, 256, 0, stream>>>(Qb, Kb, Vtb, Part);
    flash_merge_kernel<<<512, 256, 0, stream>>>(Part, Out);
}